// Round 10
// baseline (290.117 us; speedup 1.0000x reference)
//
#include <hip/hip_runtime.h>

#define FDIM 64

typedef unsigned short u16;
typedef unsigned int u32;
typedef unsigned long long u64;
typedef float v2f __attribute__((ext_vector_type(2)));

__device__ __forceinline__ u16 f2bf(float x) {          // RNE f32->bf16
    unsigned int u = __float_as_uint(x);
    return (u16)((u + 0x7fff + ((u >> 16) & 1)) >> 16);
}
__device__ __forceinline__ float bf2f(u16 h) {
    return __uint_as_float(((unsigned int)h) << 16);
}
// pack 4 f32 -> 4 fp8 e4m3 (OCP on gfx950) in one u32
__device__ __forceinline__ u32 pk_fp8x4(float a, float b, float c, float d) {
    u32 p = __builtin_amdgcn_cvt_pk_fp8_f32(a, b, 0, false);
    p = __builtin_amdgcn_cvt_pk_fp8_f32(c, d, p, true);
    return p;
}

// ========= mm compute phase (f32 As): t = As @ Ws, SPLIT fp8 out =========
// t rows split into Lo (features 0-31) / Hi (32-63), 32B each, so each
// half-array is 3.2MB and fits a per-XCD L2 (4MiB) during aggregation.

template <bool SCALE>
__device__ __forceinline__ void mm_compute(
    u32* __restrict__ tLo, u32* __restrict__ tHi,
    const int* __restrict__ cnt, int n, int r0,
    float (*__restrict__ As)[FDIM + 1], const float* __restrict__ Ws)
{
    int tid = threadIdx.x;
    int rq = tid >> 4;   // rows rq*4..+3
    int cq = tid & 15;   // cols cq*4..+3
    float acc[4][4];
    #pragma unroll
    for (int i = 0; i < 4; ++i)
        #pragma unroll
        for (int j = 0; j < 4; ++j) acc[i][j] = 0.f;

    const float4* Ws4 = (const float4*)Ws;
    #pragma unroll 4
    for (int k = 0; k < FDIM; ++k) {
        float4 w = Ws4[k * 16 + cq];
        float a[4];
        #pragma unroll
        for (int i = 0; i < 4; ++i) a[i] = As[rq * 4 + i][k];
        #pragma unroll
        for (int i = 0; i < 4; ++i) {
            acc[i][0] = fmaf(a[i], w.x, acc[i][0]);
            acc[i][1] = fmaf(a[i], w.y, acc[i][1]);
            acc[i][2] = fmaf(a[i], w.z, acc[i][2]);
            acc[i][3] = fmaf(a[i], w.w, acc[i][3]);
        }
    }

    #pragma unroll
    for (int i = 0; i < 4; ++i) {
        int R = r0 + rq * 4 + i;
        if (R < n) {
            float sc = 1.0f;
            if (SCALE) sc = rsqrtf((float)cnt[R] + 1.0f);
            u32 pk = pk_fp8x4(acc[i][0] * sc, acc[i][1] * sc,
                              acc[i][2] * sc, acc[i][3] * sc);
            if (cq < 8) tLo[(size_t)R * 8 + cq] = pk;
            else        tHi[(size_t)R * 8 + cq - 8] = pk;
        }
    }
}

// ===== mm compute phase (bf16-packed As [64][33] u32), split fp8 out =====

__device__ __forceinline__ void mm_compute_bf16(
    u32* __restrict__ tLo, u32* __restrict__ tHi,
    const int* __restrict__ cnt, int n, int r0,
    u32 (*__restrict__ Asb)[33], const float* __restrict__ Ws)
{
    int tid = threadIdx.x;
    int rq = tid >> 4;
    int cq = tid & 15;
    float acc[4][4];
    #pragma unroll
    for (int i = 0; i < 4; ++i)
        #pragma unroll
        for (int j = 0; j < 4; ++j) acc[i][j] = 0.f;

    const float4* Ws4 = (const float4*)Ws;
    #pragma unroll 4
    for (int k2 = 0; k2 < FDIM / 2; ++k2) {
        float4 w0 = Ws4[(2 * k2) * 16 + cq];
        float4 w1 = Ws4[(2 * k2 + 1) * 16 + cq];
        float a0[4], a1[4];
        #pragma unroll
        for (int i = 0; i < 4; ++i) {
            u32 pk = Asb[rq * 4 + i][k2];
            a0[i] = bf2f((u16)(pk & 0xffff));
            a1[i] = bf2f((u16)(pk >> 16));
        }
        #pragma unroll
        for (int i = 0; i < 4; ++i) {
            acc[i][0] = fmaf(a0[i], w0.x, acc[i][0]);
            acc[i][1] = fmaf(a0[i], w0.y, acc[i][1]);
            acc[i][2] = fmaf(a0[i], w0.z, acc[i][2]);
            acc[i][3] = fmaf(a0[i], w0.w, acc[i][3]);
            acc[i][0] = fmaf(a1[i], w1.x, acc[i][0]);
            acc[i][1] = fmaf(a1[i], w1.y, acc[i][1]);
            acc[i][2] = fmaf(a1[i], w1.z, acc[i][2]);
            acc[i][3] = fmaf(a1[i], w1.w, acc[i][3]);
        }
    }

    #pragma unroll
    for (int i = 0; i < 4; ++i) {
        int R = r0 + rq * 4 + i;
        if (R < n) {
            float sc = rsqrtf((float)cnt[R] + 1.0f);
            u32 pk = pk_fp8x4(acc[i][0] * sc, acc[i][1] * sc,
                              acc[i][2] * sc, acc[i][3] * sc);
            if (cq < 8) tLo[(size_t)R * 8 + cq] = pk;
            else        tHi[(size_t)R * 8 + cq - 8] = pk;
        }
    }
}

// ================= sort-based CSR build (no device atomics) ================

__global__ __launch_bounds__(256) void k_hist_mm(
    const int* __restrict__ dst, int* __restrict__ hpart,
    u32* __restrict__ tALo, u32* __restrict__ tAHi,
    u32* __restrict__ tBLo, u32* __restrict__ tBHi,
    const float* __restrict__ x, const float* __restrict__ W1,
    int n, int E, int nbuk, int hist_blocks)
{
    __shared__ float As[64][FDIM + 1];
    __shared__ float Ws[FDIM * FDIM];
    __shared__ int h[1024];

    int tid = threadIdx.x, blk = blockIdx.x;
    if ((int)blk < hist_blocks) {
        if (blk == 0 && tid < 16) {     // zero rows before each half array
            (tALo - 16)[tid] = 0u; (tAHi - 16)[tid] = 0u;
            (tBLo - 16)[tid] = 0u; (tBHi - 16)[tid] = 0u;
        }
        for (int b = tid; b < nbuk; b += 256) h[b] = 0;
        __syncthreads();
        int stride = hist_blocks * 256;
        for (int e = blk * 256 + tid; e < E; e += stride)
            atomicAdd(&h[dst[e] >> 8], 1);
        __syncthreads();
        for (int b = tid; b < nbuk; b += 256) hpart[b * 256 + blk] = h[b];
        return;
    }

    // ---- mm1: t1 = x @ W1 (fp8 out, unscaled, split) ----
    int r0 = (blk - hist_blocks) * 64;
    #pragma unroll
    for (int i = 0; i < 4; ++i)
        ((float4*)Ws)[tid + 256 * i] = ((const float4*)W1)[tid + 256 * i];
    #pragma unroll
    for (int i = 0; i < 4; ++i) {
        int idx = tid + 256 * i;
        int r = idx >> 4;
        int kq = idx & 15;
        float4 v = make_float4(0.f, 0.f, 0.f, 0.f);
        int R = r0 + r;
        if (R < n) v = ((const float4*)x)[(size_t)R * 16 + kq];
        As[r][kq * 4 + 0] = v.x;
        As[r][kq * 4 + 1] = v.y;
        As[r][kq * 4 + 2] = v.z;
        As[r][kq * 4 + 3] = v.w;
    }
    __syncthreads();
    mm_compute<false>(tALo, tAHi, nullptr, n, r0, As, Ws);
}

// per-bucket column scan (parallel over buckets)
__global__ __launch_bounds__(256) void k_scan_a(
    int* __restrict__ hpart, int* __restrict__ bb)
{
    __shared__ int s[256];
    int b = blockIdx.x;
    int tid = threadIdx.x;
    int v = hpart[(size_t)b * 256 + tid];
    s[tid] = v;
    __syncthreads();
    #pragma unroll
    for (int off = 1; off < 256; off <<= 1) {
        int w = (tid >= off) ? s[tid - off] : 0;
        __syncthreads();
        s[tid] += w;
        __syncthreads();
    }
    hpart[(size_t)b * 256 + tid] = s[tid] - v;   // exclusive, no bucket base
    if (tid == 255) bb[b] = s[255];              // bucket total
}

// scan bucket totals (supports nbuk <= 512)
__global__ __launch_bounds__(256) void k_scan_b(
    int* __restrict__ bb, int nbuk)
{
    __shared__ int s[512];
    int tid = threadIdx.x;
    s[tid]       = (tid < nbuk) ? bb[tid] : 0;
    s[tid + 256] = (tid + 256 < nbuk) ? bb[tid + 256] : 0;
    __syncthreads();
    #pragma unroll
    for (int off = 1; off < 512; off <<= 1) {
        int a0 = (tid >= off) ? s[tid - off] : 0;
        int a1 = (tid + 256 >= off) ? s[tid + 256 - off] : 0;
        __syncthreads();
        s[tid] += a0;
        s[tid + 256] += a1;
        __syncthreads();
    }
    int e0 = (tid == 0) ? 0 : s[tid - 1];
    int e1 = s[tid + 255];
    if (tid < nbuk) bb[tid] = e0;
    if (tid + 256 < nbuk) bb[tid + 256] = e1;
    if (tid == 255) bb[nbuk] = s[511];           // total = E
}

__global__ __launch_bounds__(256) void k_scatter(
    const int* __restrict__ src, const int* __restrict__ dst,
    const int* __restrict__ hpart, const int* __restrict__ bb,
    u64* __restrict__ ebuf, int E, int nbuk)
{
    __shared__ int cur[1024];
    int tid = threadIdx.x, blk = blockIdx.x;
    for (int b = tid; b < nbuk; b += 256)
        cur[b] = hpart[(size_t)b * 256 + blk] + bb[b];
    __syncthreads();
    int stride = gridDim.x * 256;
    for (int e = blk * 256 + tid; e < E; e += stride) {
        int d = dst[e], s = src[e];
        int p = atomicAdd(&cur[d >> 8], 1);          // LDS atomic
        ebuf[p] = ((u64)(u32)d << 32) | (u32)s;
    }
}

// per-bucket build: LDS count + scan -> exact cnt/rptr, compact csr
__global__ __launch_bounds__(256) void k_build(
    const u64* __restrict__ ebuf, const int* __restrict__ bb,
    int* __restrict__ cnt, int* __restrict__ rptr, int* __restrict__ csr,
    int n)
{
    __shared__ int cnt_l[256], scn[256], cur[256];
    int tid = threadIdx.x;
    int b = blockIdx.x;
    int node0 = b << 8;
    int nn = n - node0; if (nn > 256) nn = 256;
    int e0 = bb[b], e1 = bb[b + 1];

    cnt_l[tid] = 0;
    __syncthreads();
    for (int e = e0 + tid; e < e1; e += 256)
        atomicAdd(&cnt_l[(int)(ebuf[e] >> 32) & 255], 1);
    __syncthreads();
    int v = cnt_l[tid];
    scn[tid] = v;
    __syncthreads();
    #pragma unroll
    for (int off = 1; off < 256; off <<= 1) {
        int w = (tid >= off) ? scn[tid - off] : 0;
        __syncthreads();
        scn[tid] += w;
        __syncthreads();
    }
    int excl = scn[tid] - v;
    if (tid < nn) {
        cnt[node0 + tid]  = v;
        rptr[node0 + tid] = e0 + excl;
    }
    cur[tid] = e0 + excl;
    __syncthreads();
    for (int e = e0 + tid; e < e1; e += 256) {
        u64 pk = ebuf[e];
        int local = (int)(pk >> 32) & 255;
        int p = atomicAdd(&cur[local], 1);       // LDS atomic
        csr[p] = (int)(u32)(pk & 0xffffffffu);
    }
}

// ======= gather-aggregate of ONE FEATURE-HALF of one node ==================
// 16-lane group, 2 edges per gather slot: lanes 0-7 (s8=0) even edge,
// lanes 8-15 (s8=1) odd edge; each lane owns u32 f8 (4 fp8 feats) of the
// 32B half-row. Unconditional gathers; jv=-1 -> zero row at th[-8..-1].
// Returns the completed half (post shfl_xor combine, self term, *di) --
// identical value in both s8 sub-lanes.

template <bool SCALED>
__device__ __forceinline__ float4 agg_node_half(
    int i, const int* __restrict__ cnt, const int* __restrict__ rptr,
    const int* __restrict__ csr, const u32* __restrict__ th,
    int li, int nbase, int s8, int f8)
{
    int dg = cnt[i];
    float di = rsqrtf((float)dg + 1.0f);
    int m = dg;
    const int* row = csr + rptr[i];

    float4 A0 = make_float4(0.f, 0.f, 0.f, 0.f);
    float4 A1 = A0, A2 = A0, A3 = A0;

    for (int c0 = 0; c0 < m; c0 += 16) {
        int cm = m - c0; if (cm > 16) cm = 16;
        int sv = -1; float dvv = 0.f;
        if (li < cm) {
            sv = __builtin_nontemporal_load(&row[c0 + li]);
            if (!SCALED) dvv = rsqrtf((float)cnt[sv] + 1.0f);
        }
        int jv[8]; float dj[8]; u32 v[8];
        #pragma unroll
        for (int u = 0; u < 8; ++u) {
            jv[u] = __shfl(sv, nbase + 2 * u + s8);
            if (!SCALED) dj[u] = __shfl(dvv, nbase + 2 * u + s8);
        }
        #pragma unroll
        for (int u = 0; u < 8; ++u)
            v[u] = th[(long long)jv[u] * 8 + f8];   // jv=-1 -> zero row
        #pragma unroll
        for (int u = 0; u < 8; ++u) {
            v2f x0 = __builtin_amdgcn_cvt_pk_f32_fp8(v[u], false);
            v2f x1 = __builtin_amdgcn_cvt_pk_f32_fp8(v[u], true);
            float4* Ap = (u & 3) == 0 ? &A0 : (u & 3) == 1 ? &A1 :
                         (u & 3) == 2 ? &A2 : &A3;
            if (SCALED) {
                Ap->x += x0.x; Ap->y += x0.y;
                Ap->z += x1.x; Ap->w += x1.y;
            } else {
                Ap->x = fmaf(x0.x, dj[u], Ap->x);
                Ap->y = fmaf(x0.y, dj[u], Ap->y);
                Ap->z = fmaf(x1.x, dj[u], Ap->z);
                Ap->w = fmaf(x1.y, dj[u], Ap->w);
            }
        }
    }

    float4 A;
    A.x = (A0.x + A1.x) + (A2.x + A3.x);
    A.y = (A0.y + A1.y) + (A2.y + A3.y);
    A.z = (A0.z + A1.z) + (A2.z + A3.z);
    A.w = (A0.w + A1.w) + (A2.w + A3.w);
    // combine even/odd sub-lanes (lane ^ 8 stays within the 16-lane group)
    A.x += __shfl_xor(A.x, 8);
    A.y += __shfl_xor(A.y, 8);
    A.z += __shfl_xor(A.z, 8);
    A.w += __shfl_xor(A.w, 8);

    // self term
    u32 sp = th[(size_t)i * 8 + f8];
    v2f s0 = __builtin_amdgcn_cvt_pk_f32_fp8(sp, false);
    v2f s1 = __builtin_amdgcn_cvt_pk_f32_fp8(sp, true);
    if (SCALED) {
        A.x += s0.x; A.y += s0.y; A.z += s1.x; A.w += s1.y;
    } else {
        A.x = fmaf(s0.x, di, A.x); A.y = fmaf(s0.y, di, A.y);
        A.z = fmaf(s1.x, di, A.z); A.w = fmaf(s1.y, di, A.w);
    }
    A.x *= di; A.y *= di; A.z *= di; A.w *= di;
    return A;
}

// == fused aggregate + matmul, split-half gathers ==
// h-loop is TEMPORAL: all resident blocks gather from the same 3.2MB half
// at a time -> per-XCD-L2 resident. Both halves land in Asb before the mm.

template <bool SCALED_IN>
__global__ __launch_bounds__(256) void k_aggmm(
    const int* __restrict__ cnt, const int* __restrict__ rptr,
    const int* __restrict__ csr,
    const u32* __restrict__ tinLo, const u32* __restrict__ tinHi,
    const float* __restrict__ Wm, const float* __restrict__ bias,
    u32* __restrict__ toutLo, u32* __restrict__ toutHi, int n)
{
    __shared__ u32 Asb[64][33];
    __shared__ float Ws[FDIM * FDIM];
    int tid = threadIdx.x;
    #pragma unroll
    for (int i = 0; i < 4; ++i)
        ((float4*)Ws)[tid + 256 * i] = ((const float4*)Wm)[tid + 256 * i];

    int r0 = blockIdx.x * 64;
    int group = tid >> 4;          // 0..15
    int li = tid & 15;
    int nbase = ((tid & 63) >> 4) << 4;
    int s8 = li >> 3;
    int f8 = li & 7;

    #pragma unroll 1
    for (int h = 0; h < 2; ++h) {
        const u32* th = h ? tinHi : tinLo;
        float4 b = ((const float4*)bias)[h * 8 + f8];
        #pragma unroll 1
        for (int r = 0; r < 4; ++r) {
            int row = r * 16 + group;
            int i = r0 + row;
            float4 v = make_float4(0.f, 0.f, 0.f, 0.f);
            if (i < n) {
                float4 O = agg_node_half<SCALED_IN>(
                    i, cnt, rptr, csr, th, li, nbase, s8, f8);
                v.x = fmaxf(O.x + b.x, 0.f);
                v.y = fmaxf(O.y + b.y, 0.f);
                v.z = fmaxf(O.z + b.z, 0.f);
                v.w = fmaxf(O.w + b.w, 0.f);
            }
            if (s8 == 0) {
                Asb[row][h * 16 + f8 * 2 + 0] =
                    ((u32)f2bf(v.x)) | (((u32)f2bf(v.y)) << 16);
                Asb[row][h * 16 + f8 * 2 + 1] =
                    ((u32)f2bf(v.z)) | (((u32)f2bf(v.w)) << 16);
            }
        }
    }
    __syncthreads();
    mm_compute_bf16(toutLo, toutHi, cnt, n, r0, Asb, Ws);
}

// == layer-3 aggregate + pool partial-sum, split-half (NO fences) ==

__global__ __launch_bounds__(256) void k_agg_pool(
    const int* __restrict__ cnt, const int* __restrict__ rptr,
    const int* __restrict__ csr,
    const u32* __restrict__ tLo, const u32* __restrict__ tHi,
    const int* __restrict__ batch, float* __restrict__ partial,
    int n, int npart)
{
    int g = blockIdx.x / npart;
    int part = blockIdx.x - g * npart;
    int tid = threadIdx.x;

    int lo = 0, hi = n;
    while (lo < hi) { int mid = (lo + hi) >> 1; if (batch[mid] < g) lo = mid + 1; else hi = mid; }
    int start = lo;
    hi = n;
    while (lo < hi) { int mid = (lo + hi) >> 1; if (batch[mid] <= g) lo = mid + 1; else hi = mid; }
    int end = lo;

    int group = tid >> 4;     // 0..15
    int li = tid & 15;
    int nbase = ((tid & 63) >> 4) << 4;
    int s8 = li >> 3;
    int f8 = li & 7;

    __shared__ float4 red[16][16];

    #pragma unroll 1
    for (int h = 0; h < 2; ++h) {
        const u32* th = h ? tHi : tLo;
        float4 acc = make_float4(0.f, 0.f, 0.f, 0.f);
        for (int i = start + part * 16 + group; i < end; i += npart * 16) {
            float4 O = agg_node_half<true>(
                i, cnt, rptr, csr, th, li, nbase, s8, f8);
            acc.x += O.x; acc.y += O.y; acc.z += O.z; acc.w += O.w;
        }
        if (s8 == 0) red[group][h * 8 + f8] = acc;
    }
    __syncthreads();
    if (tid < 16) {
        float4 s = make_float4(0.f, 0.f, 0.f, 0.f);
        #pragma unroll
        for (int q = 0; q < 16; ++q) {
            s.x += red[q][tid].x; s.y += red[q][tid].y;
            s.z += red[q][tid].z; s.w += red[q][tid].w;
        }
        ((float4*)partial)[((size_t)g * npart + part) * 16 + tid] = s;
    }
}

// == final: reduce partials + mean + b3 + Wlin + blin, one block/graph ==

__global__ __launch_bounds__(64) void k_pool2(
    const float* __restrict__ partial, const int* __restrict__ batch,
    const float* __restrict__ b3, const float* __restrict__ Wlin,
    const float* __restrict__ blin, float* __restrict__ out,
    int n, int fout, int npart)
{
    int g = blockIdx.x;
    int tid = threadIdx.x;

    int lo = 0, hi = n;
    while (lo < hi) { int mid = (lo + hi) >> 1; if (batch[mid] < g) lo = mid + 1; else hi = mid; }
    int start = lo;
    hi = n;
    while (lo < hi) { int mid = (lo + hi) >> 1; if (batch[mid] <= g) lo = mid + 1; else hi = mid; }
    int cg = lo - start;

    __shared__ float pooled[64];
    float v = 0.f;
    for (int p = 0; p < npart; ++p)
        v += partial[((size_t)g * npart + p) * 64 + tid];
    pooled[tid] = (cg > 0) ? (v / (float)cg + b3[tid]) : 0.f;
    __syncthreads();
    if (tid < fout) {
        float o = blin[tid];
        for (int k = 0; k < 64; ++k) o += pooled[k] * Wlin[k * fout + tid];
        out[(size_t)g * fout + tid] = o;
    }
}

// ================= launcher =================

extern "C" void kernel_launch(void* const* d_in, const int* in_sizes, int n_in,
                              void* d_out, int out_size, void* d_ws, size_t ws_size,
                              hipStream_t stream) {
    const float* x     = (const float*)d_in[0];
    const int*   ei    = (const int*)d_in[1];
    const int*   batch = (const int*)d_in[2];
    const float* W1 = (const float*)d_in[3];
    const float* b1 = (const float*)d_in[4];
    const float* W2 = (const float*)d_in[5];
    const float* b2 = (const float*)d_in[6];
    const float* W3 = (const float*)d_in[7];
    const float* b3 = (const float*)d_in[8];
    const float* Wl = (const float*)d_in[9];
    const float* bl = (const float*)d_in[10];

    int n = in_sizes[0] / 64;
    int E = in_sizes[1] / 2;
    int fout = in_sizes[10];
    int ngraphs = out_size / fout;

    const int* srcp = ei;
    const int* dstp = ei + E;

    const int npart = 16;
    int nbuk = (n + 255) >> 8;                       // 256 nodes per bucket

    // ws layout (ebuf first for 8B alignment):
    // ebuf(E u64) | csr(E) | cnt(n) | rptr(n) | bb(nbuk+1) | hpart(nbuk*256)
    // | z(16) tALo(n*8) | z(16) tAHi(n*8) | z(16) tBLo(n*8) | z(16) tBHi(n*8)
    // | ppool
    u64* ebuf = (u64*)d_ws;
    int* csr  = (int*)(ebuf + (size_t)E);
    int* cnt  = csr + (size_t)E;
    int* rptr = cnt + n;
    int* bb   = rptr + n;
    int* hpart = bb + (nbuk + 1);
    u32* tALo = (u32*)(hpart + (size_t)nbuk * 256) + 16;
    u32* tAHi = tALo + (size_t)n * 8 + 16;
    u32* tBLo = tAHi + (size_t)n * 8 + 16;
    u32* tBHi = tBLo + (size_t)n * 8 + 16;
    float* ppool = (float*)(tBHi + (size_t)n * 8);   // ngraphs*npart*64

    int mm_blocks = (n + 63) / 64;
    int hist_blocks = 256;

    // --- build chain; mm1 fused into the FIRST dispatch (depends only on x)
    k_hist_mm<<<hist_blocks + mm_blocks, 256, 0, stream>>>(
        dstp, hpart, tALo, tAHi, tBLo, tBHi, x, W1, n, E, nbuk, hist_blocks);
    k_scan_a<<<nbuk, 256, 0, stream>>>(hpart, bb);
    k_scan_b<<<1, 256, 0, stream>>>(bb, nbuk);
    k_scatter<<<256, 256, 0, stream>>>(srcp, dstp, hpart, bb, ebuf, E, nbuk);
    k_build<<<nbuk, 256, 0, stream>>>(ebuf, bb, cnt, rptr, csr, n);

    // layer1 agg (unscaled t1) + layer2 matmul -> t2 (pre-scaled)
    k_aggmm<false><<<mm_blocks, 256, 0, stream>>>(
        cnt, rptr, csr, tALo, tAHi, W2, b1, tBLo, tBHi, n);
    // layer2 agg (scaled t2) + layer3 matmul -> t3 (pre-scaled)
    k_aggmm<true><<<mm_blocks, 256, 0, stream>>>(
        cnt, rptr, csr, tBLo, tBHi, W3, b2, tALo, tAHi, n);
    // layer3 agg + pool partial-sum (no fences)
    k_agg_pool<<<ngraphs * npart, 256, 0, stream>>>(
        cnt, rptr, csr, tALo, tAHi, batch, ppool, n, npart);
    // final reduce + linear
    k_pool2<<<ngraphs, 64, 0, stream>>>(ppool, batch, b3, Wl, bl,
                                        (float*)d_out, n, fout, npart);
}

// Round 11
// 244.133 us; speedup vs baseline: 1.1884x; 1.1884x over previous
//
#include <hip/hip_runtime.h>

#define FDIM 64

typedef unsigned short u16;
typedef unsigned int u32;
typedef unsigned long long u64;
typedef float v2f __attribute__((ext_vector_type(2)));

__device__ __forceinline__ u16 f2bf(float x) {          // RNE f32->bf16
    unsigned int u = __float_as_uint(x);
    return (u16)((u + 0x7fff + ((u >> 16) & 1)) >> 16);
}
__device__ __forceinline__ float bf2f(u16 h) {
    return __uint_as_float(((unsigned int)h) << 16);
}
// pack 4 f32 -> 4 fp8 e4m3 (OCP on gfx950) in one u32
__device__ __forceinline__ u32 pk_fp8x4(float a, float b, float c, float d) {
    u32 p = __builtin_amdgcn_cvt_pk_fp8_f32(a, b, 0, false);
    p = __builtin_amdgcn_cvt_pk_fp8_f32(c, d, p, true);
    return p;
}

// ========= mm compute phase (f32 As): t[64 rows] = As @ Ws (fp8 out) ======

template <bool SCALE>
__device__ __forceinline__ void mm_compute(
    u32* __restrict__ t, const int* __restrict__ cnt, int n, int r0,
    float (*__restrict__ As)[FDIM + 1], const float* __restrict__ Ws)
{
    int tid = threadIdx.x;
    int rq = tid >> 4;   // rows rq*4..+3
    int cq = tid & 15;   // cols cq*4..+3
    float acc[4][4];
    #pragma unroll
    for (int i = 0; i < 4; ++i)
        #pragma unroll
        for (int j = 0; j < 4; ++j) acc[i][j] = 0.f;

    const float4* Ws4 = (const float4*)Ws;
    #pragma unroll 4
    for (int k = 0; k < FDIM; ++k) {
        float4 w = Ws4[k * 16 + cq];
        float a[4];
        #pragma unroll
        for (int i = 0; i < 4; ++i) a[i] = As[rq * 4 + i][k];
        #pragma unroll
        for (int i = 0; i < 4; ++i) {
            acc[i][0] = fmaf(a[i], w.x, acc[i][0]);
            acc[i][1] = fmaf(a[i], w.y, acc[i][1]);
            acc[i][2] = fmaf(a[i], w.z, acc[i][2]);
            acc[i][3] = fmaf(a[i], w.w, acc[i][3]);
        }
    }

    #pragma unroll
    for (int i = 0; i < 4; ++i) {
        int R = r0 + rq * 4 + i;
        if (R < n) {
            float sc = 1.0f;
            if (SCALE) sc = rsqrtf((float)cnt[R] + 1.0f);
            t[(size_t)R * 16 + cq] =
                pk_fp8x4(acc[i][0] * sc, acc[i][1] * sc,
                         acc[i][2] * sc, acc[i][3] * sc);
        }
    }
}

// ===== mm compute phase (bf16-packed As [64][33] u32) — used by k_aggmm ===
// Cuts aggmm LDS 33KB -> ~25KB => 6 blocks/CU (was 4).

__device__ __forceinline__ void mm_compute_bf16(
    u32* __restrict__ t, const int* __restrict__ cnt, int n, int r0,
    u32 (*__restrict__ Asb)[33], const float* __restrict__ Ws)
{
    int tid = threadIdx.x;
    int rq = tid >> 4;
    int cq = tid & 15;
    float acc[4][4];
    #pragma unroll
    for (int i = 0; i < 4; ++i)
        #pragma unroll
        for (int j = 0; j < 4; ++j) acc[i][j] = 0.f;

    const float4* Ws4 = (const float4*)Ws;
    #pragma unroll 4
    for (int k2 = 0; k2 < FDIM / 2; ++k2) {
        float4 w0 = Ws4[(2 * k2) * 16 + cq];
        float4 w1 = Ws4[(2 * k2 + 1) * 16 + cq];
        float a0[4], a1[4];
        #pragma unroll
        for (int i = 0; i < 4; ++i) {
            u32 pk = Asb[rq * 4 + i][k2];
            a0[i] = bf2f((u16)(pk & 0xffff));
            a1[i] = bf2f((u16)(pk >> 16));
        }
        #pragma unroll
        for (int i = 0; i < 4; ++i) {
            acc[i][0] = fmaf(a0[i], w0.x, acc[i][0]);
            acc[i][1] = fmaf(a0[i], w0.y, acc[i][1]);
            acc[i][2] = fmaf(a0[i], w0.z, acc[i][2]);
            acc[i][3] = fmaf(a0[i], w0.w, acc[i][3]);
            acc[i][0] = fmaf(a1[i], w1.x, acc[i][0]);
            acc[i][1] = fmaf(a1[i], w1.y, acc[i][1]);
            acc[i][2] = fmaf(a1[i], w1.z, acc[i][2]);
            acc[i][3] = fmaf(a1[i], w1.w, acc[i][3]);
        }
    }

    #pragma unroll
    for (int i = 0; i < 4; ++i) {
        int R = r0 + rq * 4 + i;
        if (R < n) {
            float sc = rsqrtf((float)cnt[R] + 1.0f);
            t[(size_t)R * 16 + cq] =
                pk_fp8x4(acc[i][0] * sc, acc[i][1] * sc,
                         acc[i][2] * sc, acc[i][3] * sc);
        }
    }
}

// ================= sort-based CSR build (no device atomics) ================
// k_hist_mm: hist blocks (first 256) + mm1 blocks (independent of CSR --
// overlaps the dense matmul with the whole build chain).

__global__ __launch_bounds__(256) void k_hist_mm(
    const int* __restrict__ dst, int* __restrict__ hpart,
    u32* __restrict__ zA, u32* __restrict__ zB,
    const float* __restrict__ x, const float* __restrict__ W1,
    u32* __restrict__ t, int n, int E, int nbuk, int hist_blocks)
{
    __shared__ float As[64][FDIM + 1];
    __shared__ float Ws[FDIM * FDIM];
    __shared__ int h[1024];

    int tid = threadIdx.x, blk = blockIdx.x;
    if ((int)blk < hist_blocks) {
        if (blk == 0 && tid < 16) { zA[tid] = 0u; zB[tid] = 0u; }
        for (int b = tid; b < nbuk; b += 256) h[b] = 0;
        __syncthreads();
        int stride = hist_blocks * 256;
        for (int e = blk * 256 + tid; e < E; e += stride)
            atomicAdd(&h[dst[e] >> 8], 1);
        __syncthreads();
        for (int b = tid; b < nbuk; b += 256) hpart[b * 256 + blk] = h[b];
        return;
    }

    // ---- mm1: t = x @ W1 (fp8 out, unscaled) ----
    int r0 = (blk - hist_blocks) * 64;
    #pragma unroll
    for (int i = 0; i < 4; ++i)
        ((float4*)Ws)[tid + 256 * i] = ((const float4*)W1)[tid + 256 * i];
    #pragma unroll
    for (int i = 0; i < 4; ++i) {
        int idx = tid + 256 * i;
        int r = idx >> 4;
        int kq = idx & 15;
        float4 v = make_float4(0.f, 0.f, 0.f, 0.f);
        int R = r0 + r;
        if (R < n) v = ((const float4*)x)[(size_t)R * 16 + kq];
        As[r][kq * 4 + 0] = v.x;
        As[r][kq * 4 + 1] = v.y;
        As[r][kq * 4 + 2] = v.z;
        As[r][kq * 4 + 3] = v.w;
    }
    __syncthreads();
    mm_compute<false>(t, nullptr, n, r0, As, Ws);
}

// per-bucket column scan (parallel over buckets)
__global__ __launch_bounds__(256) void k_scan_a(
    int* __restrict__ hpart, int* __restrict__ bb)
{
    __shared__ int s[256];
    int b = blockIdx.x;
    int tid = threadIdx.x;
    int v = hpart[(size_t)b * 256 + tid];
    s[tid] = v;
    __syncthreads();
    #pragma unroll
    for (int off = 1; off < 256; off <<= 1) {
        int w = (tid >= off) ? s[tid - off] : 0;
        __syncthreads();
        s[tid] += w;
        __syncthreads();
    }
    hpart[(size_t)b * 256 + tid] = s[tid] - v;   // exclusive, no bucket base
    if (tid == 255) bb[b] = s[255];              // bucket total
}

// scan bucket totals (supports nbuk <= 512)
__global__ __launch_bounds__(256) void k_scan_b(
    int* __restrict__ bb, int nbuk)
{
    __shared__ int s[512];
    int tid = threadIdx.x;
    s[tid]       = (tid < nbuk) ? bb[tid] : 0;
    s[tid + 256] = (tid + 256 < nbuk) ? bb[tid + 256] : 0;
    __syncthreads();
    #pragma unroll
    for (int off = 1; off < 512; off <<= 1) {
        int a0 = (tid >= off) ? s[tid - off] : 0;
        int a1 = (tid + 256 >= off) ? s[tid + 256 - off] : 0;
        __syncthreads();
        s[tid] += a0;
        s[tid + 256] += a1;
        __syncthreads();
    }
    int e0 = (tid == 0) ? 0 : s[tid - 1];
    int e1 = s[tid + 255];
    if (tid < nbuk) bb[tid] = e0;
    if (tid + 256 < nbuk) bb[tid + 256] = e1;
    if (tid == 255) bb[nbuk] = s[511];           // total = E
}

__global__ __launch_bounds__(256) void k_scatter(
    const int* __restrict__ src, const int* __restrict__ dst,
    const int* __restrict__ hpart, const int* __restrict__ bb,
    u64* __restrict__ ebuf, int E, int nbuk)
{
    __shared__ int cur[1024];
    int tid = threadIdx.x, blk = blockIdx.x;
    for (int b = tid; b < nbuk; b += 256)
        cur[b] = hpart[(size_t)b * 256 + blk] + bb[b];
    __syncthreads();
    int stride = gridDim.x * 256;
    for (int e = blk * 256 + tid; e < E; e += stride) {
        int d = dst[e], s = src[e];
        int p = atomicAdd(&cur[d >> 8], 1);          // LDS atomic
        ebuf[p] = ((u64)(u32)d << 32) | (u32)s;
    }
}

// per-bucket build: LDS count + scan -> exact cnt/rptr, compact csr
__global__ __launch_bounds__(256) void k_build(
    const u64* __restrict__ ebuf, const int* __restrict__ bb,
    int* __restrict__ cnt, int* __restrict__ rptr, int* __restrict__ csr,
    int n)
{
    __shared__ int cnt_l[256], scn[256], cur[256];
    int tid = threadIdx.x;
    int b = blockIdx.x;
    int node0 = b << 8;
    int nn = n - node0; if (nn > 256) nn = 256;
    int e0 = bb[b], e1 = bb[b + 1];

    cnt_l[tid] = 0;
    __syncthreads();
    for (int e = e0 + tid; e < e1; e += 256)
        atomicAdd(&cnt_l[(int)(ebuf[e] >> 32) & 255], 1);
    __syncthreads();
    int v = cnt_l[tid];
    scn[tid] = v;
    __syncthreads();
    #pragma unroll
    for (int off = 1; off < 256; off <<= 1) {
        int w = (tid >= off) ? scn[tid - off] : 0;
        __syncthreads();
        scn[tid] += w;
        __syncthreads();
    }
    int excl = scn[tid] - v;
    if (tid < nn) {
        cnt[node0 + tid]  = v;
        rptr[node0 + tid] = e0 + excl;
    }
    cur[tid] = e0 + excl;
    __syncthreads();
    for (int e = e0 + tid; e < e1; e += 256) {
        u64 pk = ebuf[e];
        int local = (int)(pk >> 32) & 255;
        int p = atomicAdd(&cur[local], 1);       // LDS atomic
        csr[p] = (int)(u32)(pk & 0xffffffffu);
    }
}

// ======= gather-aggregate body for one node (16-lane group) ================
// Known-good round-5 pattern: fully-unconditional 16-deep gather batch per
// csr chunk; invalid lanes sv=-1 -> 64B zero row before each t buffer.
// Compact CSR: row at csr + rptr[i], exact length cnt[i].

template <bool SCALED>
__device__ __forceinline__ float4 agg_node(
    int i, const int* __restrict__ cnt, const int* __restrict__ rptr,
    const int* __restrict__ csr, const u32* __restrict__ t,
    int li, int nbase)
{
    int dg = cnt[i];
    float di = rsqrtf((float)dg + 1.0f);
    int m = dg;

    u32 sp = t[(size_t)i * 16 + li];
    v2f s0 = __builtin_amdgcn_cvt_pk_f32_fp8(sp, false);
    v2f s1 = __builtin_amdgcn_cvt_pk_f32_fp8(sp, true);
    float4 A0, A1, A2, A3;
    if (SCALED) {
        A0 = make_float4(s0.x, s0.y, s1.x, s1.y);
    } else {
        A0 = make_float4(s0.x * di, s0.y * di, s1.x * di, s1.y * di);
    }
    A1 = make_float4(0.f, 0.f, 0.f, 0.f);
    A2 = make_float4(0.f, 0.f, 0.f, 0.f);
    A3 = make_float4(0.f, 0.f, 0.f, 0.f);

    const int* row = csr + rptr[i];

    for (int c0 = 0; c0 < m; c0 += 16) {
        int cm = m - c0; if (cm > 16) cm = 16;
        int sv = -1; float dvv = 0.f;
        if (li < cm) {
            sv = __builtin_nontemporal_load(&row[c0 + li]);
            if (!SCALED) dvv = rsqrtf((float)cnt[sv] + 1.0f);
        }
        int jv[16]; float dj[16]; u32 v[16];
        #pragma unroll
        for (int u = 0; u < 16; ++u) {
            jv[u] = __shfl(sv, nbase + u);
            if (!SCALED) dj[u] = __shfl(dvv, nbase + u);
        }
        #pragma unroll
        for (int u = 0; u < 16; ++u)
            v[u] = t[(long long)jv[u] * 16 + li];   // jv=-1 -> zero row
        #pragma unroll
        for (int u = 0; u < 16; ++u) {
            v2f x0 = __builtin_amdgcn_cvt_pk_f32_fp8(v[u], false);
            v2f x1 = __builtin_amdgcn_cvt_pk_f32_fp8(v[u], true);
            float4* Ap = (u & 3) == 0 ? &A0 : (u & 3) == 1 ? &A1 :
                         (u & 3) == 2 ? &A2 : &A3;
            if (SCALED) {
                Ap->x += x0.x; Ap->y += x0.y;
                Ap->z += x1.x; Ap->w += x1.y;
            } else {
                Ap->x = fmaf(x0.x, dj[u], Ap->x);
                Ap->y = fmaf(x0.y, dj[u], Ap->y);
                Ap->z = fmaf(x1.x, dj[u], Ap->z);
                Ap->w = fmaf(x1.y, dj[u], Ap->w);
            }
        }
    }

    float4 O;
    O.x = ((A0.x + A1.x) + (A2.x + A3.x)) * di;
    O.y = ((A0.y + A1.y) + (A2.y + A3.y)) * di;
    O.z = ((A0.z + A1.z) + (A2.z + A3.z)) * di;
    O.w = ((A0.w + A1.w) + (A2.w + A3.w)) * di;
    return O;
}

// == fused aggregate + matmul: As stored as packed bf16 (LDS 33->25KB,
// 4->6 blocks/CU for latency hiding). ==

template <bool SCALED_IN>
__global__ __launch_bounds__(256) void k_aggmm(
    const int* __restrict__ cnt, const int* __restrict__ rptr,
    const int* __restrict__ csr, const u32* __restrict__ tin,
    const float* __restrict__ Wm, const float* __restrict__ bias,
    u32* __restrict__ tout, int n)
{
    __shared__ u32 Asb[64][33];
    __shared__ float Ws[FDIM * FDIM];
    int tid = threadIdx.x;
    #pragma unroll
    for (int i = 0; i < 4; ++i)
        ((float4*)Ws)[tid + 256 * i] = ((const float4*)Wm)[tid + 256 * i];

    int r0 = blockIdx.x * 64;
    int group = tid >> 4;          // 0..15
    int li = tid & 15;
    int nbase = ((tid & 63) >> 4) << 4;
    float4 b = ((const float4*)bias)[li];

    #pragma unroll 1
    for (int r = 0; r < 4; ++r) {
        int row = r * 16 + group;
        int i = r0 + row;
        float4 v = make_float4(0.f, 0.f, 0.f, 0.f);
        if (i < n) {
            float4 O = agg_node<SCALED_IN>(i, cnt, rptr, csr, tin, li, nbase);
            v.x = fmaxf(O.x + b.x, 0.f);
            v.y = fmaxf(O.y + b.y, 0.f);
            v.z = fmaxf(O.z + b.z, 0.f);
            v.w = fmaxf(O.w + b.w, 0.f);
        }
        Asb[row][li * 2 + 0] = ((u32)f2bf(v.x)) | (((u32)f2bf(v.y)) << 16);
        Asb[row][li * 2 + 1] = ((u32)f2bf(v.z)) | (((u32)f2bf(v.w)) << 16);
    }
    __syncthreads();
    mm_compute_bf16(tout, cnt, n, r0, Asb, Ws);
}

// == layer-3 aggregate + pool partial-sum (NO fences; round 3/4 lesson) ==

__global__ __launch_bounds__(256) void k_agg_pool(
    const int* __restrict__ cnt, const int* __restrict__ rptr,
    const int* __restrict__ csr, const u32* __restrict__ t,
    const int* __restrict__ batch, float* __restrict__ partial,
    int n, int npart)
{
    int g = blockIdx.x / npart;
    int part = blockIdx.x - g * npart;
    int tid = threadIdx.x;

    int lo = 0, hi = n;
    while (lo < hi) { int mid = (lo + hi) >> 1; if (batch[mid] < g) lo = mid + 1; else hi = mid; }
    int start = lo;
    hi = n;
    while (lo < hi) { int mid = (lo + hi) >> 1; if (batch[mid] <= g) lo = mid + 1; else hi = mid; }
    int end = lo;

    int group = tid >> 4;     // 0..15
    int li = tid & 15;
    int nbase = ((tid & 63) >> 4) << 4;

    float4 acc = make_float4(0.f, 0.f, 0.f, 0.f);
    for (int i = start + part * 16 + group; i < end; i += npart * 16) {
        float4 O = agg_node<true>(i, cnt, rptr, csr, t, li, nbase);
        acc.x += O.x; acc.y += O.y; acc.z += O.z; acc.w += O.w;
    }

    __shared__ float4 red[16][16];
    red[group][li] = acc;
    __syncthreads();
    if (tid < 16) {
        float4 s = make_float4(0.f, 0.f, 0.f, 0.f);
        #pragma unroll
        for (int q = 0; q < 16; ++q) {
            s.x += red[q][tid].x; s.y += red[q][tid].y;
            s.z += red[q][tid].z; s.w += red[q][tid].w;
        }
        ((float4*)partial)[((size_t)g * npart + part) * 16 + tid] = s;
    }
}

// == final: reduce partials + mean + b3 + Wlin + blin, one block/graph ==

__global__ __launch_bounds__(64) void k_pool2(
    const float* __restrict__ partial, const int* __restrict__ batch,
    const float* __restrict__ b3, const float* __restrict__ Wlin,
    const float* __restrict__ blin, float* __restrict__ out,
    int n, int fout, int npart)
{
    int g = blockIdx.x;
    int tid = threadIdx.x;

    int lo = 0, hi = n;
    while (lo < hi) { int mid = (lo + hi) >> 1; if (batch[mid] < g) lo = mid + 1; else hi = mid; }
    int start = lo;
    hi = n;
    while (lo < hi) { int mid = (lo + hi) >> 1; if (batch[mid] <= g) lo = mid + 1; else hi = mid; }
    int cg = lo - start;

    __shared__ float pooled[64];
    float v = 0.f;
    for (int p = 0; p < npart; ++p)
        v += partial[((size_t)g * npart + p) * 64 + tid];
    pooled[tid] = (cg > 0) ? (v / (float)cg + b3[tid]) : 0.f;
    __syncthreads();
    if (tid < fout) {
        float o = blin[tid];
        for (int k = 0; k < 64; ++k) o += pooled[k] * Wlin[k * fout + tid];
        out[(size_t)g * fout + tid] = o;
    }
}

// ================= launcher =================

extern "C" void kernel_launch(void* const* d_in, const int* in_sizes, int n_in,
                              void* d_out, int out_size, void* d_ws, size_t ws_size,
                              hipStream_t stream) {
    const float* x     = (const float*)d_in[0];
    const int*   ei    = (const int*)d_in[1];
    const int*   batch = (const int*)d_in[2];
    const float* W1 = (const float*)d_in[3];
    const float* b1 = (const float*)d_in[4];
    const float* W2 = (const float*)d_in[5];
    const float* b2 = (const float*)d_in[6];
    const float* W3 = (const float*)d_in[7];
    const float* b3 = (const float*)d_in[8];
    const float* Wl = (const float*)d_in[9];
    const float* bl = (const float*)d_in[10];

    int n = in_sizes[0] / 64;
    int E = in_sizes[1] / 2;
    int fout = in_sizes[10];
    int ngraphs = out_size / fout;

    const int* srcp = ei;
    const int* dstp = ei + E;

    const int npart = 16;
    int nbuk = (n + 255) >> 8;                       // 256 nodes per bucket

    // ws layout (ebuf first for 8B alignment):
    // ebuf(E u64) | csr(E) | cnt(n) | rptr(n) | bb(nbuk+1) | hpart(nbuk*256)
    // | zA(16) | tA(n*16) | zB(16) | tB(n*16) | ppool
    u64* ebuf = (u64*)d_ws;
    int* csr  = (int*)(ebuf + (size_t)E);
    int* cnt  = csr + (size_t)E;
    int* rptr = cnt + n;
    int* bb   = rptr + n;
    int* hpart = bb + (nbuk + 1);
    u32* zA  = (u32*)(hpart + (size_t)nbuk * 256);
    u32* tA  = zA + 16;
    u32* zB  = tA + (size_t)n * 16;
    u32* tB  = zB + 16;
    float* ppool = (float*)(tB + (size_t)n * 16);    // ngraphs*npart*64

    int mm_blocks = (n + 63) / 64;
    int hist_blocks = 256;

    // --- build chain; mm1 fused into the FIRST dispatch so the dense
    //     matmul overlaps hist+scan+scatter (it depends on nothing) ---
    k_hist_mm<<<hist_blocks + mm_blocks, 256, 0, stream>>>(
        dstp, hpart, zA, zB, x, W1, tA, n, E, nbuk, hist_blocks);
    k_scan_a<<<nbuk, 256, 0, stream>>>(hpart, bb);
    k_scan_b<<<1, 256, 0, stream>>>(bb, nbuk);
    k_scatter<<<256, 256, 0, stream>>>(srcp, dstp, hpart, bb, ebuf, E, nbuk);
    k_build<<<nbuk, 256, 0, stream>>>(ebuf, bb, cnt, rptr, csr, n);

    // layer1 agg (unscaled t1) + layer2 matmul -> t2 (pre-scaled)
    k_aggmm<false><<<mm_blocks, 256, 0, stream>>>(cnt, rptr, csr, tA, W2, b1, tB, n);
    // layer2 agg (scaled t2) + layer3 matmul -> t3 (pre-scaled)
    k_aggmm<true><<<mm_blocks, 256, 0, stream>>>(cnt, rptr, csr, tB, W3, b2, tA, n);
    // layer3 agg + pool partial-sum (no fences)
    k_agg_pool<<<ngraphs * npart, 256, 0, stream>>>(
        cnt, rptr, csr, tA, batch, ppool, n, npart);
    // final reduce + linear
    k_pool2<<<ngraphs, 64, 0, stream>>>(ppool, batch, b3, Wl, bl,
                                        (float*)d_out, n, fout, npart);
}